// Round 1
// baseline (474.707 us; speedup 1.0000x reference)
//
#include <hip/hip_runtime.h>

// ---------------------------------------------------------------------------
// LongContextMultiHeadAttention: B=2, S=2048, D=2048, H=16, Dh=128
// cvt(fp32->bf16) -> fused QKV GEMM (256^2 tile, 8-wave, 4-phase/K-tile,
// counted vmcnt, setprio; V written transposed; Q pre-scaled) ->
// flash attention -> O GEMM (128^2, fp32 out).
// ---------------------------------------------------------------------------

typedef __attribute__((ext_vector_type(8))) short bf16x8;
typedef __attribute__((ext_vector_type(4))) float f32x4;
typedef __attribute__((ext_vector_type(8))) unsigned short u16x8;

__device__ __forceinline__ unsigned short f2bf(float f) {  // RNE fp32->bf16
  unsigned int u = __float_as_uint(f);
  u += 0x7fffu + ((u >> 16) & 1u);
  return (unsigned short)(u >> 16);
}

#if __has_builtin(__builtin_amdgcn_cvt_pk_bf16_f32)
__device__ __forceinline__ unsigned int pack2bf(float x, float y) {
  auto r = __builtin_amdgcn_cvt_pk_bf16_f32(x, y);
  return __builtin_bit_cast(unsigned int, r);
}
#else
__device__ __forceinline__ unsigned int pack2bf(float x, float y) {
  return (unsigned int)f2bf(x) | ((unsigned int)f2bf(y) << 16);
}
#endif

__device__ __forceinline__ float fast_exp2(float x) {
#if __has_builtin(__builtin_amdgcn_exp2f)
  return __builtin_amdgcn_exp2f(x);
#else
  return exp2f(x);
#endif
}

__device__ __forceinline__ void async16(const void* g, void* l) {
  __builtin_amdgcn_global_load_lds(
      (const __attribute__((address_space(1))) unsigned int*)g,
      (__attribute__((address_space(3))) unsigned int*)l, 16, 0, 0);
}

__device__ __forceinline__ f32x4 mfma_bf16(bf16x8 a, bf16x8 b, f32x4 c) {
  return __builtin_amdgcn_mfma_f32_16x16x32_bf16(a, b, c, 0, 0, 0);
}

// ---------------------------------------------------------------------------
// fp32 -> bf16 conversion of q,k,v and the four weight matrices (one launch).
// ---------------------------------------------------------------------------
__global__ __launch_bounds__(256) void cvt_kernel(
    const float* __restrict__ q, const float* __restrict__ k,
    const float* __restrict__ v, const float* __restrict__ Wq,
    const float* __restrict__ Wk, const float* __restrict__ Wv,
    const float* __restrict__ Wo, unsigned short* __restrict__ Xq,
    unsigned short* __restrict__ Xk, unsigned short* __restrict__ Xv,
    unsigned short* __restrict__ WqB, unsigned short* __restrict__ WkB,
    unsigned short* __restrict__ WvB, unsigned short* __restrict__ WoB) {
  size_t i = ((size_t)blockIdx.x * 256 + threadIdx.x) * 8;
  const float* src;
  unsigned short* dst;
  size_t off;
  if (i < 8388608ull) { src = q; dst = Xq; off = i; }
  else if (i < 16777216ull) { src = k; dst = Xk; off = i - 8388608ull; }
  else if (i < 25165824ull) { src = v; dst = Xv; off = i - 16777216ull; }
  else if (i < 29360128ull) { src = Wq; dst = WqB; off = i - 25165824ull; }
  else if (i < 33554432ull) { src = Wk; dst = WkB; off = i - 29360128ull; }
  else if (i < 37748736ull) { src = Wv; dst = WvB; off = i - 33554432ull; }
  else { src = Wo; dst = WoB; off = i - 37748736ull; }
  f32x4 a = *(const f32x4*)(src + off);
  f32x4 b = *(const f32x4*)(src + off + 4);
  u16x8 r;
  r[0] = f2bf(a[0]); r[1] = f2bf(a[1]); r[2] = f2bf(a[2]); r[3] = f2bf(a[3]);
  r[4] = f2bf(b[0]); r[5] = f2bf(b[1]); r[6] = f2bf(b[2]); r[7] = f2bf(b[3]);
  *(u16x8*)(dst + off) = r;
}

// ---------------------------------------------------------------------------
// Fused QKV projection, 256x256 tile / BK=64 / 8 waves (2M x 4N) / 4 phases
// per K-tile with counted vmcnt (8-phase-per-2-K-tiles schedule, T3+T4+T5).
//
// LDS: S[buf][region][128x64], regions = {B-h0, B-h1, A-h0, A-h1}, each with
// the proven XOR-chunk layout (zero bank conflicts): chunk(t16,r15,cslot) at
// t16*128 + r15*8 + cslot holding data k-chunk cslot ^ (r15&7).
//
// Per K-tile t (buf = t&1):
//  P1: stage A-h1(tile t+1 -> nbuf); ds-read A mt{2,3}->AY; bar; MFMA mt{0,1}
//  P2: stage B-h0(tile t+2 -> buf);  ds-read A mt{4,5}->AX; bar; MFMA mt{2,3}
//  P3: stage B-h1(tile t+2 -> buf);  ds-read A mt{6,7}->AY; bar; MFMA mt{4,5};
//      vmcnt(4)  [exact: 2 half-tiles = 4 loads outstanding; tile t+1 landed]
//  P4: stage A-h0(tile t+2 -> buf);  ds-read A mt{0,1}(t+1)->AX; bar;
//      MFMA mt{6,7}; ds-read all B(t+1)->Bf (after MFMA: WAR on Bf); bar
// Write-after-read safety: every region's overwrite is issued >= one barrier
// after its last read (B read only at prev-P4; A-h0 last read P3, overwritten
// P4-issue whose data lands ~500cy later and region reads are lgkm-complete).
// ---------------------------------------------------------------------------
#define MFMA_PHASE(AF, MB)                                                    \
  do {                                                                        \
    __builtin_amdgcn_s_setprio(1);                                            \
    _Pragma("unroll") for (int ks = 0; ks < 2; ++ks) {                        \
      _Pragma("unroll") for (int m2 = 0; m2 < 2; ++m2) {                      \
        _Pragma("unroll") for (int nt = 0; nt < 4; ++nt) {                    \
          acc[(MB) + m2][nt] =                                                \
              mfma_bf16(AF[m2][ks], Bf[nt][ks], acc[(MB) + m2][nt]);          \
        }                                                                     \
      }                                                                       \
    }                                                                         \
    __builtin_amdgcn_s_setprio(0);                                            \
  } while (0)

__global__ __launch_bounds__(512, 2) void qkv_gemm256(
    const unsigned short* __restrict__ Xq, const unsigned short* __restrict__ Xk,
    const unsigned short* __restrict__ Xv, const unsigned short* __restrict__ Wq,
    const unsigned short* __restrict__ Wk, const unsigned short* __restrict__ Wv,
    const float* __restrict__ bq, const float* __restrict__ bk,
    const float* __restrict__ bv, unsigned short* __restrict__ Qb,
    unsigned short* __restrict__ Kb, unsigned short* __restrict__ Vt) {
  __shared__ unsigned short S[2][4][128 * 64];  // 128 KiB
  const int z = blockIdx.z;
  const unsigned short* A = z == 0 ? Xq : z == 1 ? Xk : Xv;
  const unsigned short* Bm = z == 0 ? Wq : z == 1 ? Wk : Wv;
  const float* bias = z == 0 ? bq : z == 1 ? bk : bv;
  const int m0 = blockIdx.y * 256;
  const int n0 = blockIdx.x * 256;
  const int tid = threadIdx.x;
  const int lane = tid & 63;
  const int wave = tid >> 6;
  const int quad = lane >> 4;
  const int l15 = lane & 15;
  const int wm = wave >> 2;  // 0..1
  const int wn = wave & 3;   // 0..3
  const int cxor = l15 & 7;
  const int K = 2048;

  // stage one 128x64 half-tile (16 KB): region r in {0:B-h0,1:B-h1,2:A-h0,3:A-h1}
  auto stage = [&](int r, int kt, int buf) {
#pragma unroll
    for (int p = 0; p < 2; ++p) {
      int x = p * 512 + tid;
      int row = ((x >> 7) << 4) + ((x >> 3) & 15);
      int gk = kt * 64 + (((x & 7) ^ ((x >> 3) & 7)) << 3);
      const unsigned short* src =
          (r < 2) ? Bm + (size_t)(n0 + r * 128 + row) * K + gk
                  : A + (size_t)(m0 + (r - 2) * 128 + row) * K + gk;
      async16(src, (char*)S[buf][r] + (size_t)(p * 512 + wave * 64) * 16);
    }
  };
  auto rdA = [&](int buf, int mt, int ks) -> bf16x8 {
    const unsigned short* base = S[buf][2 + wm];
    int chunk = mt * 128 + l15 * 8 + ((ks * 4 + quad) ^ cxor);
    return *(const bf16x8*)(base + chunk * 8);
  };
  auto rdB = [&](int buf, int nt, int ks) -> bf16x8 {
    const unsigned short* base = S[buf][wn >> 1];
    int chunk = ((wn & 1) * 4 + nt) * 128 + l15 * 8 + ((ks * 4 + quad) ^ cxor);
    return *(const bf16x8*)(base + chunk * 8);
  };

  f32x4 acc[8][4];
#pragma unroll
  for (int i = 0; i < 8; ++i)
#pragma unroll
    for (int j = 0; j < 4; ++j) acc[i][j] = f32x4{0.f, 0.f, 0.f, 0.f};
  bf16x8 Bf[4][2], AX[2][2], AY[2][2];

  // ---- prologue: tile0 fully + tile1 {B0,B1,A0}; gate tile0; initial frags
  stage(0, 0, 0); stage(1, 0, 0); stage(2, 0, 0); stage(3, 0, 0);
  stage(0, 1, 1); stage(1, 1, 1); stage(2, 1, 1);
  asm volatile("s_waitcnt vmcnt(6)" ::: "memory");  // tile0's 8 loads done
  __builtin_amdgcn_s_barrier();
#pragma unroll
  for (int nt = 0; nt < 4; ++nt)
#pragma unroll
    for (int ks = 0; ks < 2; ++ks) Bf[nt][ks] = rdB(0, nt, ks);
#pragma unroll
  for (int ks = 0; ks < 2; ++ks) {
    AX[0][ks] = rdA(0, 0, ks);
    AX[1][ks] = rdA(0, 1, ks);
  }

#pragma unroll 1
  for (int t = 0; t < 32; ++t) {
    const int buf = t & 1;
    const int nbuf = buf ^ 1;
    // ---- P1: MFMA mt{0,1} (AX), prefetch AY=mt{2,3}
    if (t < 31) stage(3, t + 1, nbuf);
#pragma unroll
    for (int ks = 0; ks < 2; ++ks) {
      AY[0][ks] = rdA(buf, 2, ks);
      AY[1][ks] = rdA(buf, 3, ks);
    }
    __builtin_amdgcn_sched_barrier(0);
    __builtin_amdgcn_s_barrier();
    __builtin_amdgcn_sched_barrier(0);
    MFMA_PHASE(AX, 0);
    __builtin_amdgcn_sched_barrier(0);
    __builtin_amdgcn_s_barrier();
    // ---- P2: MFMA mt{2,3} (AY), prefetch AX=mt{4,5}
    if (t < 30) stage(0, t + 2, buf);
#pragma unroll
    for (int ks = 0; ks < 2; ++ks) {
      AX[0][ks] = rdA(buf, 4, ks);
      AX[1][ks] = rdA(buf, 5, ks);
    }
    __builtin_amdgcn_sched_barrier(0);
    __builtin_amdgcn_s_barrier();
    __builtin_amdgcn_sched_barrier(0);
    MFMA_PHASE(AY, 2);
    __builtin_amdgcn_sched_barrier(0);
    __builtin_amdgcn_s_barrier();
    // ---- P3: MFMA mt{4,5} (AX), prefetch AY=mt{6,7}; vmcnt gate for tile t+1
    if (t < 30) stage(1, t + 2, buf);
#pragma unroll
    for (int ks = 0; ks < 2; ++ks) {
      AY[0][ks] = rdA(buf, 6, ks);
      AY[1][ks] = rdA(buf, 7, ks);
    }
    __builtin_amdgcn_sched_barrier(0);
    __builtin_amdgcn_s_barrier();
    __builtin_amdgcn_sched_barrier(0);
    MFMA_PHASE(AX, 4);
    if (t < 30) {
      asm volatile("s_waitcnt vmcnt(4)" ::: "memory");
    } else if (t == 30) {
      asm volatile("s_waitcnt vmcnt(0)" ::: "memory");
    }
    __builtin_amdgcn_sched_barrier(0);
    __builtin_amdgcn_s_barrier();
    // ---- P4: MFMA mt{6,7} (AY); prefetch next-tile AX=mt{0,1} before MFMA,
    //          next-tile Bf after MFMA (WAR on Bf regs)
    if (t < 30) stage(2, t + 2, buf);
    if (t < 31) {
#pragma unroll
      for (int ks = 0; ks < 2; ++ks) {
        AX[0][ks] = rdA(nbuf, 0, ks);
        AX[1][ks] = rdA(nbuf, 1, ks);
      }
    }
    __builtin_amdgcn_sched_barrier(0);
    __builtin_amdgcn_s_barrier();
    __builtin_amdgcn_sched_barrier(0);
    MFMA_PHASE(AY, 6);
    if (t < 31) {
#pragma unroll
      for (int nt = 0; nt < 4; ++nt)
#pragma unroll
        for (int ks = 0; ks < 2; ++ks) Bf[nt][ks] = rdB(nbuf, nt, ks);
    }
    __builtin_amdgcn_sched_barrier(0);
    __builtin_amdgcn_s_barrier();
  }

  // ---- epilogue
  const float SK = z == 0 ? 0.12753102331285527f : 1.0f;  // scale*log2e for Q
#pragma unroll
  for (int nt = 0; nt < 4; ++nt) {
    int col = n0 + wn * 64 + nt * 16 + l15;
    float bv_ = bias[col];
    if (z == 2) {  // V: write V^T per head, b64 (4 consecutive s)
      int h = col >> 7, d = col & 127;
#pragma unroll
      for (int mt = 0; mt < 8; ++mt) {
        int row0 = m0 + wm * 128 + mt * 16 + quad * 4;
        int bb = row0 >> 11, s = row0 & 2047;
        uint2 pk;
        pk.x = pack2bf(acc[mt][nt][0] + bv_, acc[mt][nt][1] + bv_);
        pk.y = pack2bf(acc[mt][nt][2] + bv_, acc[mt][nt][3] + bv_);
        *(uint2*)(Vt + ((size_t)((bb * 16 + h) * 128 + d)) * 2048 + s) = pk;
      }
    } else {
      unsigned short* C = z == 0 ? Qb : Kb;
#pragma unroll
      for (int mt = 0; mt < 8; ++mt) {
        int row0 = m0 + wm * 128 + mt * 16 + quad * 4;
#pragma unroll
        for (int r = 0; r < 4; ++r)
          C[(size_t)(row0 + r) * 2048 + col] = f2bf((acc[mt][nt][r] + bv_) * SK);
      }
    }
  }
}

// ---------------------------------------------------------------------------
// GEMM core (128x128, BK=64, dbuf, one barrier/K-step) — used by o_gemm.
// ---------------------------------------------------------------------------
__device__ __forceinline__ void gemm_core_k2048(
    const unsigned short* __restrict__ A, const unsigned short* __restrict__ Bm,
    int m0, int n0, unsigned short* As, unsigned short* Bs,
    f32x4 (&acc)[4][4]) {
  const int tid = threadIdx.x;
  const int lane = tid & 63;
  const int wave = tid >> 6;
  const int quad = lane >> 4;
  const int l15 = lane & 15;
  const int wmt = (wave >> 1) * 4;
  const int wnt = (wave & 1) * 4;
  const int K = 2048;

  auto stage = [&](int kt, int buf) {
    unsigned short* SA = As + buf * (128 * 64);
    unsigned short* SB = Bs + buf * (128 * 64);
#pragma unroll
    for (int p = 0; p < 4; ++p) {
      int x = p * 256 + tid;
      int row = ((x >> 7) << 4) + ((x >> 3) & 15);
      int gk = kt + (((x & 7) ^ ((x >> 3) & 7)) << 3);
      async16(A + (size_t)(m0 + row) * K + gk,
              (char*)SA + (size_t)(p * 256 + wave * 64) * 16);
      async16(Bm + (size_t)(n0 + row) * K + gk,
              (char*)SB + (size_t)(p * 256 + wave * 64) * 16);
    }
  };
  stage(0, 0);
#pragma unroll 1
  for (int it = 0; it < 32; ++it) {
    __syncthreads();
    if (it + 1 < 32) stage((it + 1) * 64, (it + 1) & 1);
    const unsigned short* SA = As + (it & 1) * (128 * 64);
    const unsigned short* SB = Bs + (it & 1) * (128 * 64);
#pragma unroll
    for (int s = 0; s < 2; ++s) {
      const int cs = (s * 4 + quad) ^ (l15 & 7);
      bf16x8 af[4], bfr[4];
#pragma unroll
      for (int t = 0; t < 4; ++t) {
        af[t] = *(const bf16x8*)(SA + ((wmt + t) * 128 + l15 * 8 + cs) * 8);
        bfr[t] = *(const bf16x8*)(SB + ((wnt + t) * 128 + l15 * 8 + cs) * 8);
      }
#pragma unroll
      for (int mt = 0; mt < 4; ++mt)
#pragma unroll
        for (int nt = 0; nt < 4; ++nt)
          acc[mt][nt] = mfma_bf16(af[mt], bfr[nt], acc[mt][nt]);
    }
  }
}

// ---------------------------------------------------------------------------
// Output projection: fp32 result.
// ---------------------------------------------------------------------------
__global__ __launch_bounds__(256, 2) void o_gemm(
    const unsigned short* __restrict__ A, const unsigned short* __restrict__ Bm,
    const float* __restrict__ bias, float* __restrict__ Cf) {
  __shared__ unsigned short As[2][128 * 64];
  __shared__ unsigned short Bs[2][128 * 64];
  const int m0 = blockIdx.y * 128;
  const int n0 = blockIdx.x * 128;

  f32x4 acc[4][4];
#pragma unroll
  for (int i = 0; i < 4; ++i)
#pragma unroll
    for (int j = 0; j < 4; ++j) acc[i][j] = f32x4{0.f, 0.f, 0.f, 0.f};
  gemm_core_k2048(A, Bm, m0, n0, As[0], Bs[0], acc);

  const int lane = threadIdx.x & 63;
  const int wave = threadIdx.x >> 6;
  const int quad = lane >> 4;
  const int l15 = lane & 15;
  const int wmt = (wave >> 1) * 4;
  const int wnt = (wave & 1) * 4;
  const int N = 2048;
#pragma unroll
  for (int nt = 0; nt < 4; ++nt) {
    int col = n0 + (wnt + nt) * 16 + l15;
    float bv_ = bias[col];
#pragma unroll
    for (int mt = 0; mt < 4; ++mt) {
      int row0 = m0 + (wmt + mt) * 16 + quad * 4;
#pragma unroll
      for (int r = 0; r < 4; ++r)
        Cf[(size_t)(row0 + r) * N + col] = acc[mt][nt][r] + bv_;
    }
  }
}

// ---------------------------------------------------------------------------
// Flash attention. Block = (b, h, 128 q-rows); 4 waves x 32 q-rows.
// KV tile 64, double-buffered staging (one barrier per tile).
// ---------------------------------------------------------------------------
__global__ __launch_bounds__(256, 2) void attn_kernel(
    const unsigned short* __restrict__ Qg, const unsigned short* __restrict__ Kg,
    const unsigned short* __restrict__ Vt, unsigned short* __restrict__ ctx) {
  __shared__ unsigned short Ks[2][64 * 128];
  __shared__ unsigned short Vs[2][128 * 64];
  __shared__ unsigned short Ps[128 * 64];
  const int tid = threadIdx.x;
  const int lane = tid & 63;
  const int wave = tid >> 6;
  const int quad = lane >> 4;
  const int l15 = lane & 15;
  const int qt = blockIdx.x, h = blockIdx.y, b = blockIdx.z;
  const int q0 = qt * 128;
  const int swz = (l15 & 7) * 8;

  bf16x8 aq[2][4];
#pragma unroll
  for (int mt = 0; mt < 2; ++mt) {
    const unsigned short* qrow =
        Qg + (size_t)(b * 2048 + q0 + wave * 32 + mt * 16 + l15) * 2048 + h * 128;
#pragma unroll
    for (int ks = 0; ks < 4; ++ks)
      aq[mt][ks] = *(const bf16x8*)(qrow + ks * 32 + quad * 8);
  }

  f32x4 o[2][8];
#pragma unroll
  for (int mt = 0; mt < 2; ++mt)
#pragma unroll
    for (int dt = 0; dt < 8; ++dt) o[mt][dt] = f32x4{0.f, 0.f, 0.f, 0.f};
  f32x4 lacc[2] = {f32x4{0.f, 0.f, 0.f, 0.f}, f32x4{0.f, 0.f, 0.f, 0.f}};

  auto stage = [&](int t, int buf) {
#pragma unroll
    for (int p = 0; p < 4; ++p) {
      int slot = p * 256 + tid;
      {
        int nt = slot >> 8, c = (slot >> 4) & 15, r15 = slot & 15;
        const unsigned short* g =
            Kg + (size_t)(b * 2048 + t * 64 + nt * 16 + r15) * 2048 + h * 128 + c * 8;
        async16(g, (char*)Ks[buf] + (size_t)(p * 256 + wave * 64) * 16);
      }
      {
        int dt = slot >> 7, c = (slot >> 4) & 7, n15 = slot & 15;
        const unsigned short* g =
            Vt + ((size_t)(b * 16 + h) * 128 + dt * 16 + n15) * 2048 + t * 64 + c * 8;
        async16(g, (char*)Vs[buf] + (size_t)(p * 256 + wave * 64) * 16);
      }
    }
  };
  stage(0, 0);

  for (int t = 0; t < 32; ++t) {
    __syncthreads();
    if (t + 1 < 32) stage(t + 1, (t + 1) & 1);
    const unsigned short* Kb = Ks[t & 1];
    const unsigned short* Vb = Vs[t & 1];

    f32x4 sc[2][4];
#pragma unroll
    for (int nt = 0; nt < 4; ++nt) {
      sc[0][nt] = f32x4{0.f, 0.f, 0.f, 0.f};
      sc[1][nt] = f32x4{0.f, 0.f, 0.f, 0.f};
#pragma unroll
      for (int ks = 0; ks < 4; ++ks) {
        bf16x8 bk = *(const bf16x8*)(Kb + (nt * 256 + (ks * 4 + quad) * 16 + l15) * 8);
        sc[0][nt] = mfma_bf16(bk, aq[0][ks], sc[0][nt]);
        sc[1][nt] = mfma_bf16(bk, aq[1][ks], sc[1][nt]);
      }
    }

#pragma unroll
    for (int mt = 0; mt < 2; ++mt) {
      int prow = (wave * 32 + mt * 16 + l15) * 64;
#pragma unroll
      for (int nt = 0; nt < 4; ++nt) {
        f32x4 p;
#pragma unroll
        for (int r = 0; r < 4; ++r) p[r] = fast_exp2(sc[mt][nt][r]);
        lacc[mt] += p;
        uint2 pk;
        pk.x = pack2bf(p[0], p[1]);
        pk.y = pack2bf(p[2], p[3]);
        *(uint2*)(Ps + prow + ((nt * 16 + quad * 4) ^ swz)) = pk;
      }
    }

    bf16x8 ap[2][2];
#pragma unroll
    for (int mt = 0; mt < 2; ++mt) {
      int prow = (wave * 32 + mt * 16 + l15) * 64;
#pragma unroll
      for (int ks = 0; ks < 2; ++ks)
        ap[mt][ks] = *(const bf16x8*)(Ps + prow + ((ks * 32 + quad * 8) ^ swz));
    }
#pragma unroll
    for (int dt = 0; dt < 8; ++dt) {
#pragma unroll
      for (int ks = 0; ks < 2; ++ks) {
        bf16x8 bv = *(const bf16x8*)(Vb + (dt * 128 + (ks * 4 + quad) * 16 + l15) * 8);
        o[0][dt] = mfma_bf16(ap[0][ks], bv, o[0][dt]);
        o[1][dt] = mfma_bf16(ap[1][ks], bv, o[1][dt]);
      }
    }
  }

  float lq[2];
#pragma unroll
  for (int mt = 0; mt < 2; ++mt) {
    float s = lacc[mt][0] + lacc[mt][1] + lacc[mt][2] + lacc[mt][3];
    s += __shfl_xor(s, 16, 64);
    s += __shfl_xor(s, 32, 64);
    lq[mt] = s;
  }

#pragma unroll
  for (int mt = 0; mt < 2; ++mt) {
#pragma unroll
    for (int r = 0; r < 4; ++r) {
      float lr = __shfl(lq[mt], quad * 4 + r, 64);
      float inv = 1.0f / lr;
      unsigned short* crow =
          ctx + (size_t)(b * 2048 + q0 + wave * 32 + mt * 16 + quad * 4 + r) * 2048 +
          h * 128;
#pragma unroll
      for (int dt = 0; dt < 8; ++dt)
        crow[dt * 16 + l15] = f2bf(o[mt][dt][r] * inv);
    }
  }
}

// ---------------------------------------------------------------------------
extern "C" void kernel_launch(void* const* d_in, const int* in_sizes, int n_in,
                              void* d_out, int out_size, void* d_ws,
                              size_t ws_size, hipStream_t stream) {
  const float* q = (const float*)d_in[0];
  const float* k = (const float*)d_in[1];
  const float* v = (const float*)d_in[2];
  const float* Wq = (const float*)d_in[3];
  const float* bq = (const float*)d_in[4];
  const float* Wk = (const float*)d_in[5];
  const float* bk = (const float*)d_in[6];
  const float* Wv = (const float*)d_in[7];
  const float* bv = (const float*)d_in[8];
  const float* Wo = (const float*)d_in[9];
  const float* bo = (const float*)d_in[10];
  float* out = (float*)d_out;

  char* ws = (char*)d_ws;
  const size_t MB = 1024 * 1024;
  unsigned short* Xq  = (unsigned short*)(ws + 0 * MB);
  unsigned short* Xk  = (unsigned short*)(ws + 16 * MB);
  unsigned short* Xv  = (unsigned short*)(ws + 32 * MB);
  unsigned short* WqB = (unsigned short*)(ws + 48 * MB);
  unsigned short* WkB = (unsigned short*)(ws + 56 * MB);
  unsigned short* WvB = (unsigned short*)(ws + 64 * MB);
  unsigned short* WoB = (unsigned short*)(ws + 72 * MB);
  unsigned short* Qb  = (unsigned short*)(ws + 80 * MB);
  unsigned short* Kb  = (unsigned short*)(ws + 96 * MB);
  unsigned short* Vt  = (unsigned short*)(ws + 112 * MB);
  unsigned short* ctx = Xq;  // Xq dead after QKV projection

  cvt_kernel<<<20480, 256, 0, stream>>>(q, k, v, Wq, Wk, Wv, Wo, Xq, Xk, Xv,
                                        WqB, WkB, WvB, WoB);
  qkv_gemm256<<<dim3(8, 16, 3), 512, 0, stream>>>(Xq, Xk, Xv, WqB, WkB, WvB,
                                                  bq, bk, bv, Qb, Kb, Vt);
  attn_kernel<<<dim3(16, 16, 2), 256, 0, stream>>>(Qb, Kb, Vt, ctx);
  o_gemm<<<dim3(16, 32), 256, 0, stream>>>(ctx, WoB, bo, out);
}

// Round 2
// 467.600 us; speedup vs baseline: 1.0152x; 1.0152x over previous
//
#include <hip/hip_runtime.h>

// ---------------------------------------------------------------------------
// LongContextMultiHeadAttention: B=2, S=2048, D=2048, H=16, Dh=128
// cvt(fp32->bf16) -> fused QKV GEMM (256^2, 8-wave, m201-style 4-phase/K-tile,
// derived counted vmcnt, setprio, NO sched_barrier) -> flash attn -> O GEMM.
// ---------------------------------------------------------------------------

typedef __attribute__((ext_vector_type(8))) short bf16x8;
typedef __attribute__((ext_vector_type(4))) float f32x4;
typedef __attribute__((ext_vector_type(8))) unsigned short u16x8;

__device__ __forceinline__ unsigned short f2bf(float f) {  // RNE fp32->bf16
  unsigned int u = __float_as_uint(f);
  u += 0x7fffu + ((u >> 16) & 1u);
  return (unsigned short)(u >> 16);
}

#if __has_builtin(__builtin_amdgcn_cvt_pk_bf16_f32)
__device__ __forceinline__ unsigned int pack2bf(float x, float y) {
  auto r = __builtin_amdgcn_cvt_pk_bf16_f32(x, y);
  return __builtin_bit_cast(unsigned int, r);
}
#else
__device__ __forceinline__ unsigned int pack2bf(float x, float y) {
  return (unsigned int)f2bf(x) | ((unsigned int)f2bf(y) << 16);
}
#endif

__device__ __forceinline__ float fast_exp2(float x) {
#if __has_builtin(__builtin_amdgcn_exp2f)
  return __builtin_amdgcn_exp2f(x);
#else
  return exp2f(x);
#endif
}

__device__ __forceinline__ void async16(const void* g, void* l) {
  __builtin_amdgcn_global_load_lds(
      (const __attribute__((address_space(1))) unsigned int*)g,
      (__attribute__((address_space(3))) unsigned int*)l, 16, 0, 0);
}

__device__ __forceinline__ f32x4 mfma_bf16(bf16x8 a, bf16x8 b, f32x4 c) {
  return __builtin_amdgcn_mfma_f32_16x16x32_bf16(a, b, c, 0, 0, 0);
}

// ---------------------------------------------------------------------------
// fp32 -> bf16 conversion of q,k,v and the four weight matrices (one launch).
// ---------------------------------------------------------------------------
__global__ __launch_bounds__(256) void cvt_kernel(
    const float* __restrict__ q, const float* __restrict__ k,
    const float* __restrict__ v, const float* __restrict__ Wq,
    const float* __restrict__ Wk, const float* __restrict__ Wv,
    const float* __restrict__ Wo, unsigned short* __restrict__ Xq,
    unsigned short* __restrict__ Xk, unsigned short* __restrict__ Xv,
    unsigned short* __restrict__ WqB, unsigned short* __restrict__ WkB,
    unsigned short* __restrict__ WvB, unsigned short* __restrict__ WoB) {
  size_t i = ((size_t)blockIdx.x * 256 + threadIdx.x) * 8;
  const float* src;
  unsigned short* dst;
  size_t off;
  if (i < 8388608ull) { src = q; dst = Xq; off = i; }
  else if (i < 16777216ull) { src = k; dst = Xk; off = i - 8388608ull; }
  else if (i < 25165824ull) { src = v; dst = Xv; off = i - 16777216ull; }
  else if (i < 29360128ull) { src = Wq; dst = WqB; off = i - 25165824ull; }
  else if (i < 33554432ull) { src = Wk; dst = WkB; off = i - 29360128ull; }
  else if (i < 37748736ull) { src = Wv; dst = WvB; off = i - 33554432ull; }
  else { src = Wo; dst = WoB; off = i - 37748736ull; }
  f32x4 a = *(const f32x4*)(src + off);
  f32x4 b = *(const f32x4*)(src + off + 4);
  u16x8 r;
  r[0] = f2bf(a[0]); r[1] = f2bf(a[1]); r[2] = f2bf(a[2]); r[3] = f2bf(a[3]);
  r[4] = f2bf(b[0]); r[5] = f2bf(b[1]); r[6] = f2bf(b[2]); r[7] = f2bf(b[3]);
  *(u16x8*)(dst + off) = r;
}

// ---------------------------------------------------------------------------
// Fused QKV projection, 256x256 / BK=64 / 8 waves / m201-style 4-phase/K-tile.
//
// LDS S[buf][region][128x64], regions {0:B-h0(cols0-127), 1:B-h1(cols128-255),
// 2:A-h0(rows0-127), 3:A-h1(rows128-255)}; XOR-chunk layout (0 conflicts):
// chunk(t16,r15,cslot) at t16*128+r15*8+cslot holds data k-chunk cslot^(r15&7).
//
// Per-wave output 128x64 spread over both halves: A rows mh*128+wm*64+m*16,
// B cols nh*128+wn*32+n*16, so quadrant (mh,nh) <-> LDS region, enabling the
// staggered staging below.
//
// Group t (buf=t&1), quadrant order (0,0),(1,0),(1,1),(0,1):
//  p0: rdA(reg2)x8+rdB(reg0)x4; stage A-h0(t+1)->nbuf; bar; 16 MFMA; bar
//  p1: rdA(reg3)x8;             stage B-h1(t+1)->nbuf; bar; 16 MFMA; bar
//  p2: rdB(reg1)x4;             stage B-h0(t+2)->buf;  bar; 16 MFMA; bar
//      (buf reg0's last read was p0 -> WAR-safe)
//  p3: rdA(reg2)x8;             stage A-h1(t+2)->buf;  vmcnt(4); bar; 16 MFMA;
//      bar   (buf reg3's last read was p1; vmcnt leaves p2+p3 stages = 4
//             outstanding -> tile t+1 halves (p0,p1 + prev group) complete)
//  t=30: vmcnt(0) (p2/p3 stages skipped; drain tile-31 halves).
// ---------------------------------------------------------------------------
__global__ __launch_bounds__(512, 2) void qkv_gemm256(
    const unsigned short* __restrict__ Xq, const unsigned short* __restrict__ Xk,
    const unsigned short* __restrict__ Xv, const unsigned short* __restrict__ Wq,
    const unsigned short* __restrict__ Wk, const unsigned short* __restrict__ Wv,
    const float* __restrict__ bq, const float* __restrict__ bk,
    const float* __restrict__ bv, unsigned short* __restrict__ Qb,
    unsigned short* __restrict__ Kb, unsigned short* __restrict__ Vt) {
  __shared__ unsigned short S[2][4][128 * 64];  // 128 KiB
  const int z = blockIdx.z;
  const unsigned short* A = z == 0 ? Xq : z == 1 ? Xk : Xv;
  const unsigned short* Bm = z == 0 ? Wq : z == 1 ? Wk : Wv;
  const float* bias = z == 0 ? bq : z == 1 ? bk : bv;
  const int m0 = blockIdx.y * 256;
  const int n0 = blockIdx.x * 256;
  const int tid = threadIdx.x;
  const int lane = tid & 63;
  const int wave = tid >> 6;
  const int quad = lane >> 4;
  const int l15 = lane & 15;
  const int wm = wave >> 2;  // 0..1
  const int wn = wave & 3;   // 0..3
  const int cxor = l15 & 7;
  const int K = 2048;

  // stage one 128x64 half-tile (16 KB), region r in {0,1:B / 2,3:A}
  auto stage = [&](int r, int kt, int buf) {
#pragma unroll
    for (int p = 0; p < 2; ++p) {
      int x = p * 512 + tid;
      int row = ((x >> 7) << 4) + ((x >> 3) & 15);
      int gk = kt * 64 + (((x & 7) ^ ((x >> 3) & 7)) << 3);
      const unsigned short* src =
          (r < 2) ? Bm + (size_t)(n0 + r * 128 + row) * K + gk
                  : A + (size_t)(m0 + (r - 2) * 128 + row) * K + gk;
      async16(src, (char*)S[buf][r] + (size_t)(p * 512 + wave * 64) * 16);
    }
  };
  auto rdA = [&](int buf, int mh, int m, int ks) -> bf16x8 {
    const unsigned short* base = S[buf][2 + mh];
    int chunk = (wm * 4 + m) * 128 + l15 * 8 + ((ks * 4 + quad) ^ cxor);
    return *(const bf16x8*)(base + chunk * 8);
  };
  auto rdB = [&](int buf, int nh, int n, int ks) -> bf16x8 {
    const unsigned short* base = S[buf][nh];
    int chunk = (wn * 2 + n) * 128 + l15 * 8 + ((ks * 4 + quad) ^ cxor);
    return *(const bf16x8*)(base + chunk * 8);
  };

  f32x4 acc[8][4];
#pragma unroll
  for (int i = 0; i < 8; ++i)
#pragma unroll
    for (int j = 0; j < 4; ++j) acc[i][j] = f32x4{0.f, 0.f, 0.f, 0.f};
  bf16x8 Af[4][2], Bfr[2][2];

  // ---- prologue: tile0 all 4 halves, then tile1 {B-h0, A-h1}
  stage(2, 0, 0); stage(1, 0, 0); stage(0, 0, 0); stage(3, 0, 0);
  stage(0, 1, 1); stage(3, 1, 1);
  asm volatile("s_waitcnt vmcnt(4)" ::: "memory");  // tile0 complete
  __builtin_amdgcn_s_barrier();

#pragma unroll 1
  for (int t = 0; t < 32; ++t) {
    const int buf = t & 1;
    const int nbuf = buf ^ 1;
    // ---- p0: quadrant (mh0, nh0)
#pragma unroll
    for (int m = 0; m < 4; ++m)
#pragma unroll
      for (int ks = 0; ks < 2; ++ks) Af[m][ks] = rdA(buf, 0, m, ks);
#pragma unroll
    for (int n = 0; n < 2; ++n)
#pragma unroll
      for (int ks = 0; ks < 2; ++ks) Bfr[n][ks] = rdB(buf, 0, n, ks);
    if (t + 1 < 32) stage(2, t + 1, nbuf);
    __builtin_amdgcn_s_barrier();
    __builtin_amdgcn_s_setprio(1);
#pragma unroll
    for (int ks = 0; ks < 2; ++ks)
#pragma unroll
      for (int m = 0; m < 4; ++m)
#pragma unroll
        for (int n = 0; n < 2; ++n)
          acc[m][n] = mfma_bf16(Af[m][ks], Bfr[n][ks], acc[m][n]);
    __builtin_amdgcn_s_setprio(0);
    __builtin_amdgcn_s_barrier();
    // ---- p1: quadrant (mh1, nh0)
#pragma unroll
    for (int m = 0; m < 4; ++m)
#pragma unroll
      for (int ks = 0; ks < 2; ++ks) Af[m][ks] = rdA(buf, 1, m, ks);
    if (t + 1 < 32) stage(1, t + 1, nbuf);
    __builtin_amdgcn_s_barrier();
    __builtin_amdgcn_s_setprio(1);
#pragma unroll
    for (int ks = 0; ks < 2; ++ks)
#pragma unroll
      for (int m = 0; m < 4; ++m)
#pragma unroll
        for (int n = 0; n < 2; ++n)
          acc[4 + m][n] = mfma_bf16(Af[m][ks], Bfr[n][ks], acc[4 + m][n]);
    __builtin_amdgcn_s_setprio(0);
    __builtin_amdgcn_s_barrier();
    // ---- p2: quadrant (mh1, nh1)
#pragma unroll
    for (int n = 0; n < 2; ++n)
#pragma unroll
      for (int ks = 0; ks < 2; ++ks) Bfr[n][ks] = rdB(buf, 1, n, ks);
    if (t + 2 < 32) stage(0, t + 2, buf);
    __builtin_amdgcn_s_barrier();
    __builtin_amdgcn_s_setprio(1);
#pragma unroll
    for (int ks = 0; ks < 2; ++ks)
#pragma unroll
      for (int m = 0; m < 4; ++m)
#pragma unroll
        for (int n = 0; n < 2; ++n)
          acc[4 + m][2 + n] = mfma_bf16(Af[m][ks], Bfr[n][ks], acc[4 + m][2 + n]);
    __builtin_amdgcn_s_setprio(0);
    __builtin_amdgcn_s_barrier();
    // ---- p3: quadrant (mh0, nh1)
#pragma unroll
    for (int m = 0; m < 4; ++m)
#pragma unroll
      for (int ks = 0; ks < 2; ++ks) Af[m][ks] = rdA(buf, 0, m, ks);
    if (t + 2 < 32) stage(3, t + 2, buf);
    if (t < 30) {
      asm volatile("s_waitcnt vmcnt(4)" ::: "memory");
    } else if (t == 30) {
      asm volatile("s_waitcnt vmcnt(0)" ::: "memory");
    }
    __builtin_amdgcn_s_barrier();
    __builtin_amdgcn_s_setprio(1);
#pragma unroll
    for (int ks = 0; ks < 2; ++ks)
#pragma unroll
      for (int m = 0; m < 4; ++m)
#pragma unroll
        for (int n = 0; n < 2; ++n)
          acc[m][2 + n] = mfma_bf16(Af[m][ks], Bfr[n][ks], acc[m][2 + n]);
    __builtin_amdgcn_s_setprio(0);
    __builtin_amdgcn_s_barrier();
  }

  // ---- epilogue
  const float SK = z == 0 ? 0.12753102331285527f : 1.0f;  // scale*log2e for Q
#pragma unroll
  for (int nf = 0; nf < 4; ++nf) {
    int col = n0 + (nf >> 1) * 128 + wn * 32 + (nf & 1) * 16 + l15;
    float bv_ = bias[col];
    if (z == 2) {  // V: write V^T per head, b64 (4 consecutive s)
      int h = col >> 7, d = col & 127;
#pragma unroll
      for (int mf = 0; mf < 8; ++mf) {
        int row0 = m0 + (mf >> 2) * 128 + wm * 64 + (mf & 3) * 16 + quad * 4;
        int bb = row0 >> 11, s = row0 & 2047;
        uint2 pk;
        pk.x = pack2bf(acc[mf][nf][0] + bv_, acc[mf][nf][1] + bv_);
        pk.y = pack2bf(acc[mf][nf][2] + bv_, acc[mf][nf][3] + bv_);
        *(uint2*)(Vt + ((size_t)((bb * 16 + h) * 128 + d)) * 2048 + s) = pk;
      }
    } else {
      unsigned short* C = z == 0 ? Qb : Kb;
#pragma unroll
      for (int mf = 0; mf < 8; ++mf) {
        int row0 = m0 + (mf >> 2) * 128 + wm * 64 + (mf & 3) * 16 + quad * 4;
#pragma unroll
        for (int r = 0; r < 4; ++r)
          C[(size_t)(row0 + r) * 2048 + col] = f2bf((acc[mf][nf][r] + bv_) * SK);
      }
    }
  }
}

// ---------------------------------------------------------------------------
// GEMM core (128x128, BK=64, dbuf, one barrier/K-step) — used by o_gemm.
// ---------------------------------------------------------------------------
__device__ __forceinline__ void gemm_core_k2048(
    const unsigned short* __restrict__ A, const unsigned short* __restrict__ Bm,
    int m0, int n0, unsigned short* As, unsigned short* Bs,
    f32x4 (&acc)[4][4]) {
  const int tid = threadIdx.x;
  const int lane = tid & 63;
  const int wave = tid >> 6;
  const int quad = lane >> 4;
  const int l15 = lane & 15;
  const int wmt = (wave >> 1) * 4;
  const int wnt = (wave & 1) * 4;
  const int K = 2048;

  auto stage = [&](int kt, int buf) {
    unsigned short* SA = As + buf * (128 * 64);
    unsigned short* SB = Bs + buf * (128 * 64);
#pragma unroll
    for (int p = 0; p < 4; ++p) {
      int x = p * 256 + tid;
      int row = ((x >> 7) << 4) + ((x >> 3) & 15);
      int gk = kt + (((x & 7) ^ ((x >> 3) & 7)) << 3);
      async16(A + (size_t)(m0 + row) * K + gk,
              (char*)SA + (size_t)(p * 256 + wave * 64) * 16);
      async16(Bm + (size_t)(n0 + row) * K + gk,
              (char*)SB + (size_t)(p * 256 + wave * 64) * 16);
    }
  };
  stage(0, 0);
#pragma unroll 1
  for (int it = 0; it < 32; ++it) {
    __syncthreads();
    if (it + 1 < 32) stage((it + 1) * 64, (it + 1) & 1);
    const unsigned short* SA = As + (it & 1) * (128 * 64);
    const unsigned short* SB = Bs + (it & 1) * (128 * 64);
#pragma unroll
    for (int s = 0; s < 2; ++s) {
      const int cs = (s * 4 + quad) ^ (l15 & 7);
      bf16x8 af[4], bfr[4];
#pragma unroll
      for (int t = 0; t < 4; ++t) {
        af[t] = *(const bf16x8*)(SA + ((wmt + t) * 128 + l15 * 8 + cs) * 8);
        bfr[t] = *(const bf16x8*)(SB + ((wnt + t) * 128 + l15 * 8 + cs) * 8);
      }
#pragma unroll
      for (int mt = 0; mt < 4; ++mt)
#pragma unroll
        for (int nt = 0; nt < 4; ++nt)
          acc[mt][nt] = mfma_bf16(af[mt], bfr[nt], acc[mt][nt]);
    }
  }
}

// ---------------------------------------------------------------------------
// Output projection: fp32 result.
// ---------------------------------------------------------------------------
__global__ __launch_bounds__(256, 2) void o_gemm(
    const unsigned short* __restrict__ A, const unsigned short* __restrict__ Bm,
    const float* __restrict__ bias, float* __restrict__ Cf) {
  __shared__ unsigned short As[2][128 * 64];
  __shared__ unsigned short Bs[2][128 * 64];
  const int m0 = blockIdx.y * 128;
  const int n0 = blockIdx.x * 128;

  f32x4 acc[4][4];
#pragma unroll
  for (int i = 0; i < 4; ++i)
#pragma unroll
    for (int j = 0; j < 4; ++j) acc[i][j] = f32x4{0.f, 0.f, 0.f, 0.f};
  gemm_core_k2048(A, Bm, m0, n0, As[0], Bs[0], acc);

  const int lane = threadIdx.x & 63;
  const int wave = threadIdx.x >> 6;
  const int quad = lane >> 4;
  const int l15 = lane & 15;
  const int wmt = (wave >> 1) * 4;
  const int wnt = (wave & 1) * 4;
  const int N = 2048;
#pragma unroll
  for (int nt = 0; nt < 4; ++nt) {
    int col = n0 + (wnt + nt) * 16 + l15;
    float bv_ = bias[col];
#pragma unroll
    for (int mt = 0; mt < 4; ++mt) {
      int row0 = m0 + (wmt + mt) * 16 + quad * 4;
#pragma unroll
      for (int r = 0; r < 4; ++r)
        Cf[(size_t)(row0 + r) * N + col] = acc[mt][nt][r] + bv_;
    }
  }
}

// ---------------------------------------------------------------------------
// Flash attention. Block = (b, h, 128 q-rows); 4 waves x 32 q-rows.
// ---------------------------------------------------------------------------
__global__ __launch_bounds__(256, 2) void attn_kernel(
    const unsigned short* __restrict__ Qg, const unsigned short* __restrict__ Kg,
    const unsigned short* __restrict__ Vt, unsigned short* __restrict__ ctx) {
  __shared__ unsigned short Ks[2][64 * 128];
  __shared__ unsigned short Vs[2][128 * 64];
  __shared__ unsigned short Ps[128 * 64];
  const int tid = threadIdx.x;
  const int lane = tid & 63;
  const int wave = tid >> 6;
  const int quad = lane >> 4;
  const int l15 = lane & 15;
  const int qt = blockIdx.x, h = blockIdx.y, b = blockIdx.z;
  const int q0 = qt * 128;
  const int swz = (l15 & 7) * 8;

  bf16x8 aq[2][4];
#pragma unroll
  for (int mt = 0; mt < 2; ++mt) {
    const unsigned short* qrow =
        Qg + (size_t)(b * 2048 + q0 + wave * 32 + mt * 16 + l15) * 2048 + h * 128;
#pragma unroll
    for (int ks = 0; ks < 4; ++ks)
      aq[mt][ks] = *(const bf16x8*)(qrow + ks * 32 + quad * 8);
  }

  f32x4 o[2][8];
#pragma unroll
  for (int mt = 0; mt < 2; ++mt)
#pragma unroll
    for (int dt = 0; dt < 8; ++dt) o[mt][dt] = f32x4{0.f, 0.f, 0.f, 0.f};
  f32x4 lacc[2] = {f32x4{0.f, 0.f, 0.f, 0.f}, f32x4{0.f, 0.f, 0.f, 0.f}};

  auto stage = [&](int t, int buf) {
#pragma unroll
    for (int p = 0; p < 4; ++p) {
      int slot = p * 256 + tid;
      {
        int nt = slot >> 8, c = (slot >> 4) & 15, r15 = slot & 15;
        const unsigned short* g =
            Kg + (size_t)(b * 2048 + t * 64 + nt * 16 + r15) * 2048 + h * 128 + c * 8;
        async16(g, (char*)Ks[buf] + (size_t)(p * 256 + wave * 64) * 16);
      }
      {
        int dt = slot >> 7, c = (slot >> 4) & 7, n15 = slot & 15;
        const unsigned short* g =
            Vt + ((size_t)(b * 16 + h) * 128 + dt * 16 + n15) * 2048 + t * 64 + c * 8;
        async16(g, (char*)Vs[buf] + (size_t)(p * 256 + wave * 64) * 16);
      }
    }
  };
  stage(0, 0);

  for (int t = 0; t < 32; ++t) {
    __syncthreads();
    if (t + 1 < 32) stage(t + 1, (t + 1) & 1);
    const unsigned short* Kb = Ks[t & 1];
    const unsigned short* Vb = Vs[t & 1];

    f32x4 sc[2][4];
#pragma unroll
    for (int nt = 0; nt < 4; ++nt) {
      sc[0][nt] = f32x4{0.f, 0.f, 0.f, 0.f};
      sc[1][nt] = f32x4{0.f, 0.f, 0.f, 0.f};
#pragma unroll
      for (int ks = 0; ks < 4; ++ks) {
        bf16x8 bk = *(const bf16x8*)(Kb + (nt * 256 + (ks * 4 + quad) * 16 + l15) * 8);
        sc[0][nt] = mfma_bf16(bk, aq[0][ks], sc[0][nt]);
        sc[1][nt] = mfma_bf16(bk, aq[1][ks], sc[1][nt]);
      }
    }

#pragma unroll
    for (int mt = 0; mt < 2; ++mt) {
      int prow = (wave * 32 + mt * 16 + l15) * 64;
#pragma unroll
      for (int nt = 0; nt < 4; ++nt) {
        f32x4 p;
#pragma unroll
        for (int r = 0; r < 4; ++r) p[r] = fast_exp2(sc[mt][nt][r]);
        lacc[mt] += p;
        uint2 pk;
        pk.x = pack2bf(p[0], p[1]);
        pk.y = pack2bf(p[2], p[3]);
        *(uint2*)(Ps + prow + ((nt * 16 + quad * 4) ^ swz)) = pk;
      }
    }

    bf16x8 ap[2][2];
#pragma unroll
    for (int mt = 0; mt < 2; ++mt) {
      int prow = (wave * 32 + mt * 16 + l15) * 64;
#pragma unroll
      for (int ks = 0; ks < 2; ++ks)
        ap[mt][ks] = *(const bf16x8*)(Ps + prow + ((ks * 32 + quad * 8) ^ swz));
    }
#pragma unroll
    for (int dt = 0; dt < 8; ++dt) {
#pragma unroll
      for (int ks = 0; ks < 2; ++ks) {
        bf16x8 bv = *(const bf16x8*)(Vb + (dt * 128 + (ks * 4 + quad) * 16 + l15) * 8);
        o[0][dt] = mfma_bf16(ap[0][ks], bv, o[0][dt]);
        o[1][dt] = mfma_bf16(ap[1][ks], bv, o[1][dt]);
      }
    }
  }

  float lq[2];
#pragma unroll
  for (int mt = 0; mt < 2; ++mt) {
    float s = lacc[mt][0] + lacc[mt][1] + lacc[mt][2] + lacc[mt][3];
    s += __shfl_xor(s, 16, 64);
    s += __shfl_xor(s, 32, 64);
    lq[mt] = s;
  }

#pragma unroll
  for (int mt = 0; mt < 2; ++mt) {
#pragma unroll
    for (int r = 0; r < 4; ++r) {
      float lr = __shfl(lq[mt], quad * 4 + r, 64);
      float inv = 1.0f / lr;
      unsigned short* crow =
          ctx + (size_t)(b * 2048 + q0 + wave * 32 + mt * 16 + quad * 4 + r) * 2048 +
          h * 128;
#pragma unroll
      for (int dt = 0; dt < 8; ++dt)
        crow[dt * 16 + l15] = f2bf(o[mt][dt][r] * inv);
    }
  }
}

// ---------------------------------------------------------------------------
extern "C" void kernel_launch(void* const* d_in, const int* in_sizes, int n_in,
                              void* d_out, int out_size, void* d_ws,
                              size_t ws_size, hipStream_t stream) {
  const float* q = (const float*)d_in[0];
  const float* k = (const float*)d_in[1];
  const float* v = (const float*)d_in[2];
  const float* Wq = (const float*)d_in[3];
  const float* bq = (const float*)d_in[4];
  const float* Wk = (const float*)d_in[5];
  const float* bk = (const float*)d_in[6];
  const float* Wv = (const float*)d_in[7];
  const float* bv = (const float*)d_in[8];
  const float* Wo = (const float*)d_in[9];
  const float* bo = (const float*)d_in[10];
  float* out = (float*)d_out;

  char* ws = (char*)d_ws;
  const size_t MB = 1024 * 1024;
  unsigned short* Xq  = (unsigned short*)(ws + 0 * MB);
  unsigned short* Xk  = (unsigned short*)(ws + 16 * MB);
  unsigned short* Xv  = (unsigned short*)(ws + 32 * MB);
  unsigned short* WqB = (unsigned short*)(ws + 48 * MB);
  unsigned short* WkB = (unsigned short*)(ws + 56 * MB);
  unsigned short* WvB = (unsigned short*)(ws + 64 * MB);
  unsigned short* WoB = (unsigned short*)(ws + 72 * MB);
  unsigned short* Qb  = (unsigned short*)(ws + 80 * MB);
  unsigned short* Kb  = (unsigned short*)(ws + 96 * MB);
  unsigned short* Vt  = (unsigned short*)(ws + 112 * MB);
  unsigned short* ctx = Xq;  // Xq dead after QKV projection

  cvt_kernel<<<20480, 256, 0, stream>>>(q, k, v, Wq, Wk, Wv, Wo, Xq, Xk, Xv,
                                        WqB, WkB, WvB, WoB);
  qkv_gemm256<<<dim3(8, 16, 3), 512, 0, stream>>>(Xq, Xk, Xv, WqB, WkB, WvB,
                                                  bq, bk, bv, Qb, Kb, Vt);
  attn_kernel<<<dim3(16, 16, 2), 256, 0, stream>>>(Qb, Kb, Vt, ctx);
  o_gemm<<<dim3(16, 32), 256, 0, stream>>>(ctx, WoB, bo, out);
}

// Round 3
// 464.857 us; speedup vs baseline: 1.0212x; 1.0059x over previous
//
#include <hip/hip_runtime.h>

// ---------------------------------------------------------------------------
// LongContextMultiHeadAttention: B=2, S=2048, D=2048, H=16, Dh=128
// cvt(fp32->bf16) -> fused QKV GEMM (256^2, 8-wave, 4-phase/K-tile, deep
// counted-vmcnt pipeline: every half-tile 6-7 phases in flight, gate vmcnt(6))
// -> flash attention -> O GEMM (128^2, fp32 out).
// ---------------------------------------------------------------------------

typedef __attribute__((ext_vector_type(8))) short bf16x8;
typedef __attribute__((ext_vector_type(4))) float f32x4;
typedef __attribute__((ext_vector_type(8))) unsigned short u16x8;

__device__ __forceinline__ unsigned short f2bf(float f) {  // RNE fp32->bf16
  unsigned int u = __float_as_uint(f);
  u += 0x7fffu + ((u >> 16) & 1u);
  return (unsigned short)(u >> 16);
}

#if __has_builtin(__builtin_amdgcn_cvt_pk_bf16_f32)
__device__ __forceinline__ unsigned int pack2bf(float x, float y) {
  auto r = __builtin_amdgcn_cvt_pk_bf16_f32(x, y);
  return __builtin_bit_cast(unsigned int, r);
}
#else
__device__ __forceinline__ unsigned int pack2bf(float x, float y) {
  return (unsigned int)f2bf(x) | ((unsigned int)f2bf(y) << 16);
}
#endif

__device__ __forceinline__ float fast_exp2(float x) {
#if __has_builtin(__builtin_amdgcn_exp2f)
  return __builtin_amdgcn_exp2f(x);
#else
  return exp2f(x);
#endif
}

__device__ __forceinline__ void async16(const void* g, void* l) {
  __builtin_amdgcn_global_load_lds(
      (const __attribute__((address_space(1))) unsigned int*)g,
      (__attribute__((address_space(3))) unsigned int*)l, 16, 0, 0);
}

__device__ __forceinline__ f32x4 mfma_bf16(bf16x8 a, bf16x8 b, f32x4 c) {
  return __builtin_amdgcn_mfma_f32_16x16x32_bf16(a, b, c, 0, 0, 0);
}

// ---------------------------------------------------------------------------
// fp32 -> bf16 conversion of q,k,v and the four weight matrices (one launch).
// ---------------------------------------------------------------------------
__global__ __launch_bounds__(256) void cvt_kernel(
    const float* __restrict__ q, const float* __restrict__ k,
    const float* __restrict__ v, const float* __restrict__ Wq,
    const float* __restrict__ Wk, const float* __restrict__ Wv,
    const float* __restrict__ Wo, unsigned short* __restrict__ Xq,
    unsigned short* __restrict__ Xk, unsigned short* __restrict__ Xv,
    unsigned short* __restrict__ WqB, unsigned short* __restrict__ WkB,
    unsigned short* __restrict__ WvB, unsigned short* __restrict__ WoB) {
  size_t i = ((size_t)blockIdx.x * 256 + threadIdx.x) * 8;
  const float* src;
  unsigned short* dst;
  size_t off;
  if (i < 8388608ull) { src = q; dst = Xq; off = i; }
  else if (i < 16777216ull) { src = k; dst = Xk; off = i - 8388608ull; }
  else if (i < 25165824ull) { src = v; dst = Xv; off = i - 16777216ull; }
  else if (i < 29360128ull) { src = Wq; dst = WqB; off = i - 25165824ull; }
  else if (i < 33554432ull) { src = Wk; dst = WkB; off = i - 29360128ull; }
  else if (i < 37748736ull) { src = Wv; dst = WvB; off = i - 33554432ull; }
  else { src = Wo; dst = WoB; off = i - 37748736ull; }
  f32x4 a = *(const f32x4*)(src + off);
  f32x4 b = *(const f32x4*)(src + off + 4);
  u16x8 r;
  r[0] = f2bf(a[0]); r[1] = f2bf(a[1]); r[2] = f2bf(a[2]); r[3] = f2bf(a[3]);
  r[4] = f2bf(b[0]); r[5] = f2bf(b[1]); r[6] = f2bf(b[2]); r[7] = f2bf(b[3]);
  *(u16x8*)(dst + off) = r;
}

// ---------------------------------------------------------------------------
// Fused QKV projection, 256x256 / BK=64 / 8 waves / 4 phases per K-tile.
//
// LDS S[buf][region][128x64], regions {0:B-h0, 1:B-h1, 2:A-h0, 3:A-h1};
// XOR-chunk layout (0 bank conflicts). Per-wave output 128x64: A rows
// mh*128+wm*64+m*16, B cols nh*128+wn*32+n*16.
//
// Quadrant order (0,0),(0,1),(1,1),(1,0) with Af + two B sets (Bf0,Bf1):
// each region read in exactly ONE phase: reg2@p0, reg0@p0(+p3 reg-reuse,
// no LDS re-read), reg1@p1, reg3@p2; reads/group = 24 b128.
//
// Staging (group t): p0: reg0(t+1)->nbuf; p1: reg2(t+2)->buf;
// p2: reg1(t+2)->buf; p3: reg3(t+2)->buf. Every stage issues exactly one
// phase AFTER its region's last read (WAR margin >= 1 barrier). Pipeline
// depth: A-halves 6-7 phases (~500cy, covers HBM/L3 A-panel latency);
// the one short half (3 phases) is reg0 = B/weights = L2-resident (~200cy;
// same-x blocks land on one XCD, so W panels are L2-hot).
// Gate: vmcnt(6) at p3 (3 newest stages may fly; tile t+1 complete);
// vmcnt(0) at t==30; no stages/gate at t==31.
// ---------------------------------------------------------------------------
__global__ __launch_bounds__(512, 2) void qkv_gemm256(
    const unsigned short* __restrict__ Xq, const unsigned short* __restrict__ Xk,
    const unsigned short* __restrict__ Xv, const unsigned short* __restrict__ Wq,
    const unsigned short* __restrict__ Wk, const unsigned short* __restrict__ Wv,
    const float* __restrict__ bq, const float* __restrict__ bk,
    const float* __restrict__ bv, unsigned short* __restrict__ Qb,
    unsigned short* __restrict__ Kb, unsigned short* __restrict__ Vt) {
  __shared__ unsigned short S[2][4][128 * 64];  // 128 KiB
  const int z = blockIdx.z;
  const unsigned short* A = z == 0 ? Xq : z == 1 ? Xk : Xv;
  const unsigned short* Bm = z == 0 ? Wq : z == 1 ? Wk : Wv;
  const float* bias = z == 0 ? bq : z == 1 ? bk : bv;
  const int m0 = blockIdx.y * 256;
  const int n0 = blockIdx.x * 256;
  const int tid = threadIdx.x;
  const int lane = tid & 63;
  const int wave = tid >> 6;
  const int quad = lane >> 4;
  const int l15 = lane & 15;
  const int wm = wave >> 2;  // 0..1
  const int wn = wave & 3;   // 0..3
  const int cxor = l15 & 7;
  const int K = 2048;

  // stage one 128x64 half-tile (16 KB), region r in {0,1:B / 2,3:A}
  auto stage = [&](int r, int kt, int buf) {
#pragma unroll
    for (int p = 0; p < 2; ++p) {
      int x = p * 512 + tid;
      int row = ((x >> 7) << 4) + ((x >> 3) & 15);
      int gk = kt * 64 + (((x & 7) ^ ((x >> 3) & 7)) << 3);
      const unsigned short* src =
          (r < 2) ? Bm + (size_t)(n0 + r * 128 + row) * K + gk
                  : A + (size_t)(m0 + (r - 2) * 128 + row) * K + gk;
      async16(src, (char*)S[buf][r] + (size_t)(p * 512 + wave * 64) * 16);
    }
  };
  auto rdA = [&](int buf, int mh, int m, int ks) -> bf16x8 {
    const unsigned short* base = S[buf][2 + mh];
    int chunk = (wm * 4 + m) * 128 + l15 * 8 + ((ks * 4 + quad) ^ cxor);
    return *(const bf16x8*)(base + chunk * 8);
  };
  auto rdB = [&](int buf, int nh, int n, int ks) -> bf16x8 {
    const unsigned short* base = S[buf][nh];
    int chunk = (wn * 2 + n) * 128 + l15 * 8 + ((ks * 4 + quad) ^ cxor);
    return *(const bf16x8*)(base + chunk * 8);
  };

  f32x4 acc[8][4];
#pragma unroll
  for (int i = 0; i < 8; ++i)
#pragma unroll
    for (int j = 0; j < 4; ++j) acc[i][j] = f32x4{0.f, 0.f, 0.f, 0.f};
  bf16x8 Af[4][2], Bf0[2][2], Bf1[2][2];

  // ---- prologue: tile0 all 4 halves; tile1 {reg2, reg1, reg3}
  stage(2, 0, 0); stage(0, 0, 0); stage(1, 0, 0); stage(3, 0, 0);
  stage(2, 1, 1); stage(1, 1, 1); stage(3, 1, 1);
  asm volatile("s_waitcnt vmcnt(6)" ::: "memory");  // tile0 complete
  __builtin_amdgcn_s_barrier();

#pragma unroll 1
  for (int t = 0; t < 32; ++t) {
    const int buf = t & 1;
    const int nbuf = buf ^ 1;
    // ---- p0: quadrant (mh0, nh0); stage reg0(t+1) [region freed p3(t-1)]
#pragma unroll
    for (int m = 0; m < 4; ++m)
#pragma unroll
      for (int ks = 0; ks < 2; ++ks) Af[m][ks] = rdA(buf, 0, m, ks);
#pragma unroll
    for (int n = 0; n < 2; ++n)
#pragma unroll
      for (int ks = 0; ks < 2; ++ks) Bf0[n][ks] = rdB(buf, 0, n, ks);
    if (t + 1 < 32) stage(0, t + 1, nbuf);
    __builtin_amdgcn_s_barrier();
    __builtin_amdgcn_s_setprio(1);
#pragma unroll
    for (int ks = 0; ks < 2; ++ks)
#pragma unroll
      for (int m = 0; m < 4; ++m)
#pragma unroll
        for (int n = 0; n < 2; ++n)
          acc[m][n] = mfma_bf16(Af[m][ks], Bf0[n][ks], acc[m][n]);
    __builtin_amdgcn_s_setprio(0);
    __builtin_amdgcn_s_barrier();
    // ---- p1: quadrant (mh0, nh1); stage reg2(t+2) [freed p0]
#pragma unroll
    for (int n = 0; n < 2; ++n)
#pragma unroll
      for (int ks = 0; ks < 2; ++ks) Bf1[n][ks] = rdB(buf, 1, n, ks);
    if (t + 2 < 32) stage(2, t + 2, buf);
    __builtin_amdgcn_s_barrier();
    __builtin_amdgcn_s_setprio(1);
#pragma unroll
    for (int ks = 0; ks < 2; ++ks)
#pragma unroll
      for (int m = 0; m < 4; ++m)
#pragma unroll
        for (int n = 0; n < 2; ++n)
          acc[m][2 + n] = mfma_bf16(Af[m][ks], Bf1[n][ks], acc[m][2 + n]);
    __builtin_amdgcn_s_setprio(0);
    __builtin_amdgcn_s_barrier();
    // ---- p2: quadrant (mh1, nh1); stage reg1(t+2) [freed p1]
#pragma unroll
    for (int m = 0; m < 4; ++m)
#pragma unroll
      for (int ks = 0; ks < 2; ++ks) Af[m][ks] = rdA(buf, 1, m, ks);
    if (t + 2 < 32) stage(1, t + 2, buf);
    __builtin_amdgcn_s_barrier();
    __builtin_amdgcn_s_setprio(1);
#pragma unroll
    for (int ks = 0; ks < 2; ++ks)
#pragma unroll
      for (int m = 0; m < 4; ++m)
#pragma unroll
        for (int n = 0; n < 2; ++n)
          acc[4 + m][2 + n] = mfma_bf16(Af[m][ks], Bf1[n][ks], acc[4 + m][2 + n]);
    __builtin_amdgcn_s_setprio(0);
    __builtin_amdgcn_s_barrier();
    // ---- p3: quadrant (mh1, nh0) [Af + Bf0 both already in regs];
    //          stage reg3(t+2) [freed p2]; gate once per K-tile
    if (t + 2 < 32) stage(3, t + 2, buf);
    if (t < 30) {
      asm volatile("s_waitcnt vmcnt(6)" ::: "memory");
    } else if (t == 30) {
      asm volatile("s_waitcnt vmcnt(0)" ::: "memory");
    }
    __builtin_amdgcn_s_barrier();
    __builtin_amdgcn_s_setprio(1);
#pragma unroll
    for (int ks = 0; ks < 2; ++ks)
#pragma unroll
      for (int m = 0; m < 4; ++m)
#pragma unroll
        for (int n = 0; n < 2; ++n)
          acc[4 + m][n] = mfma_bf16(Af[m][ks], Bf0[n][ks], acc[4 + m][n]);
    __builtin_amdgcn_s_setprio(0);
    __builtin_amdgcn_s_barrier();
  }

  // ---- epilogue
  const float SK = z == 0 ? 0.12753102331285527f : 1.0f;  // scale*log2e for Q
#pragma unroll
  for (int nf = 0; nf < 4; ++nf) {
    int col = n0 + (nf >> 1) * 128 + wn * 32 + (nf & 1) * 16 + l15;
    float bv_ = bias[col];
    if (z == 2) {  // V: write V^T per head, b64 (4 consecutive s)
      int h = col >> 7, d = col & 127;
#pragma unroll
      for (int mf = 0; mf < 8; ++mf) {
        int row0 = m0 + (mf >> 2) * 128 + wm * 64 + (mf & 3) * 16 + quad * 4;
        int bb = row0 >> 11, s = row0 & 2047;
        uint2 pk;
        pk.x = pack2bf(acc[mf][nf][0] + bv_, acc[mf][nf][1] + bv_);
        pk.y = pack2bf(acc[mf][nf][2] + bv_, acc[mf][nf][3] + bv_);
        *(uint2*)(Vt + ((size_t)((bb * 16 + h) * 128 + d)) * 2048 + s) = pk;
      }
    } else {
      unsigned short* C = z == 0 ? Qb : Kb;
#pragma unroll
      for (int mf = 0; mf < 8; ++mf) {
        int row0 = m0 + (mf >> 2) * 128 + wm * 64 + (mf & 3) * 16 + quad * 4;
#pragma unroll
        for (int r = 0; r < 4; ++r)
          C[(size_t)(row0 + r) * 2048 + col] = f2bf((acc[mf][nf][r] + bv_) * SK);
      }
    }
  }
}

// ---------------------------------------------------------------------------
// GEMM core (128x128, BK=64, dbuf, one barrier/K-step) — used by o_gemm.
// ---------------------------------------------------------------------------
__device__ __forceinline__ void gemm_core_k2048(
    const unsigned short* __restrict__ A, const unsigned short* __restrict__ Bm,
    int m0, int n0, unsigned short* As, unsigned short* Bs,
    f32x4 (&acc)[4][4]) {
  const int tid = threadIdx.x;
  const int lane = tid & 63;
  const int wave = tid >> 6;
  const int quad = lane >> 4;
  const int l15 = lane & 15;
  const int wmt = (wave >> 1) * 4;
  const int wnt = (wave & 1) * 4;
  const int K = 2048;

  auto stage = [&](int kt, int buf) {
    unsigned short* SA = As + buf * (128 * 64);
    unsigned short* SB = Bs + buf * (128 * 64);
#pragma unroll
    for (int p = 0; p < 4; ++p) {
      int x = p * 256 + tid;
      int row = ((x >> 7) << 4) + ((x >> 3) & 15);
      int gk = kt + (((x & 7) ^ ((x >> 3) & 7)) << 3);
      async16(A + (size_t)(m0 + row) * K + gk,
              (char*)SA + (size_t)(p * 256 + wave * 64) * 16);
      async16(Bm + (size_t)(n0 + row) * K + gk,
              (char*)SB + (size_t)(p * 256 + wave * 64) * 16);
    }
  };
  stage(0, 0);
#pragma unroll 1
  for (int it = 0; it < 32; ++it) {
    __syncthreads();
    if (it + 1 < 32) stage((it + 1) * 64, (it + 1) & 1);
    const unsigned short* SA = As + (it & 1) * (128 * 64);
    const unsigned short* SB = Bs + (it & 1) * (128 * 64);
#pragma unroll
    for (int s = 0; s < 2; ++s) {
      const int cs = (s * 4 + quad) ^ (l15 & 7);
      bf16x8 af[4], bfr[4];
#pragma unroll
      for (int t = 0; t < 4; ++t) {
        af[t] = *(const bf16x8*)(SA + ((wmt + t) * 128 + l15 * 8 + cs) * 8);
        bfr[t] = *(const bf16x8*)(SB + ((wnt + t) * 128 + l15 * 8 + cs) * 8);
      }
#pragma unroll
      for (int mt = 0; mt < 4; ++mt)
#pragma unroll
        for (int nt = 0; nt < 4; ++nt)
          acc[mt][nt] = mfma_bf16(af[mt], bfr[nt], acc[mt][nt]);
    }
  }
}

// ---------------------------------------------------------------------------
// Output projection: fp32 result.
// ---------------------------------------------------------------------------
__global__ __launch_bounds__(256, 2) void o_gemm(
    const unsigned short* __restrict__ A, const unsigned short* __restrict__ Bm,
    const float* __restrict__ bias, float* __restrict__ Cf) {
  __shared__ unsigned short As[2][128 * 64];
  __shared__ unsigned short Bs[2][128 * 64];
  const int m0 = blockIdx.y * 128;
  const int n0 = blockIdx.x * 128;

  f32x4 acc[4][4];
#pragma unroll
  for (int i = 0; i < 4; ++i)
#pragma unroll
    for (int j = 0; j < 4; ++j) acc[i][j] = f32x4{0.f, 0.f, 0.f, 0.f};
  gemm_core_k2048(A, Bm, m0, n0, As[0], Bs[0], acc);

  const int lane = threadIdx.x & 63;
  const int wave = threadIdx.x >> 6;
  const int quad = lane >> 4;
  const int l15 = lane & 15;
  const int wmt = (wave >> 1) * 4;
  const int wnt = (wave & 1) * 4;
  const int N = 2048;
#pragma unroll
  for (int nt = 0; nt < 4; ++nt) {
    int col = n0 + (wnt + nt) * 16 + l15;
    float bv_ = bias[col];
#pragma unroll
    for (int mt = 0; mt < 4; ++mt) {
      int row0 = m0 + (wmt + mt) * 16 + quad * 4;
#pragma unroll
      for (int r = 0; r < 4; ++r)
        Cf[(size_t)(row0 + r) * N + col] = acc[mt][nt][r] + bv_;
    }
  }
}

// ---------------------------------------------------------------------------
// Flash attention. Block = (b, h, 128 q-rows); 4 waves x 32 q-rows.
// ---------------------------------------------------------------------------
__global__ __launch_bounds__(256, 2) void attn_kernel(
    const unsigned short* __restrict__ Qg, const unsigned short* __restrict__ Kg,
    const unsigned short* __restrict__ Vt, unsigned short* __restrict__ ctx) {
  __shared__ unsigned short Ks[2][64 * 128];
  __shared__ unsigned short Vs[2][128 * 64];
  __shared__ unsigned short Ps[128 * 64];
  const int tid = threadIdx.x;
  const int lane = tid & 63;
  const int wave = tid >> 6;
  const int quad = lane >> 4;
  const int l15 = lane & 15;
  const int qt = blockIdx.x, h = blockIdx.y, b = blockIdx.z;
  const int q0 = qt * 128;
  const int swz = (l15 & 7) * 8;

  bf16x8 aq[2][4];
#pragma unroll
  for (int mt = 0; mt < 2; ++mt) {
    const unsigned short* qrow =
        Qg + (size_t)(b * 2048 + q0 + wave * 32 + mt * 16 + l15) * 2048 + h * 128;
#pragma unroll
    for (int ks = 0; ks < 4; ++ks)
      aq[mt][ks] = *(const bf16x8*)(qrow + ks * 32 + quad * 8);
  }

  f32x4 o[2][8];
#pragma unroll
  for (int mt = 0; mt < 2; ++mt)
#pragma unroll
    for (int dt = 0; dt < 8; ++dt) o[mt][dt] = f32x4{0.f, 0.f, 0.f, 0.f};
  f32x4 lacc[2] = {f32x4{0.f, 0.f, 0.f, 0.f}, f32x4{0.f, 0.f, 0.f, 0.f}};

  auto stage = [&](int t, int buf) {
#pragma unroll
    for (int p = 0; p < 4; ++p) {
      int slot = p * 256 + tid;
      {
        int nt = slot >> 8, c = (slot >> 4) & 15, r15 = slot & 15;
        const unsigned short* g =
            Kg + (size_t)(b * 2048 + t * 64 + nt * 16 + r15) * 2048 + h * 128 + c * 8;
        async16(g, (char*)Ks[buf] + (size_t)(p * 256 + wave * 64) * 16);
      }
      {
        int dt = slot >> 7, c = (slot >> 4) & 7, n15 = slot & 15;
        const unsigned short* g =
            Vt + ((size_t)(b * 16 + h) * 128 + dt * 16 + n15) * 2048 + t * 64 + c * 8;
        async16(g, (char*)Vs[buf] + (size_t)(p * 256 + wave * 64) * 16);
      }
    }
  };
  stage(0, 0);

  for (int t = 0; t < 32; ++t) {
    __syncthreads();
    if (t + 1 < 32) stage(t + 1, (t + 1) & 1);
    const unsigned short* Kb = Ks[t & 1];
    const unsigned short* Vb = Vs[t & 1];

    f32x4 sc[2][4];
#pragma unroll
    for (int nt = 0; nt < 4; ++nt) {
      sc[0][nt] = f32x4{0.f, 0.f, 0.f, 0.f};
      sc[1][nt] = f32x4{0.f, 0.f, 0.f, 0.f};
#pragma unroll
      for (int ks = 0; ks < 4; ++ks) {
        bf16x8 bk = *(const bf16x8*)(Kb + (nt * 256 + (ks * 4 + quad) * 16 + l15) * 8);
        sc[0][nt] = mfma_bf16(bk, aq[0][ks], sc[0][nt]);
        sc[1][nt] = mfma_bf16(bk, aq[1][ks], sc[1][nt]);
      }
    }

#pragma unroll
    for (int mt = 0; mt < 2; ++mt) {
      int prow = (wave * 32 + mt * 16 + l15) * 64;
#pragma unroll
      for (int nt = 0; nt < 4; ++nt) {
        f32x4 p;
#pragma unroll
        for (int r = 0; r < 4; ++r) p[r] = fast_exp2(sc[mt][nt][r]);
        lacc[mt] += p;
        uint2 pk;
        pk.x = pack2bf(p[0], p[1]);
        pk.y = pack2bf(p[2], p[3]);
        *(uint2*)(Ps + prow + ((nt * 16 + quad * 4) ^ swz)) = pk;
      }
    }

    bf16x8 ap[2][2];
#pragma unroll
    for (int mt = 0; mt < 2; ++mt) {
      int prow = (wave * 32 + mt * 16 + l15) * 64;
#pragma unroll
      for (int ks = 0; ks < 2; ++ks)
        ap[mt][ks] = *(const bf16x8*)(Ps + prow + ((ks * 32 + quad * 8) ^ swz));
    }
#pragma unroll
    for (int dt = 0; dt < 8; ++dt) {
#pragma unroll
      for (int ks = 0; ks < 2; ++ks) {
        bf16x8 bv = *(const bf16x8*)(Vb + (dt * 128 + (ks * 4 + quad) * 16 + l15) * 8);
        o[0][dt] = mfma_bf16(ap[0][ks], bv, o[0][dt]);
        o[1][dt] = mfma_bf16(ap[1][ks], bv, o[1][dt]);
      }
    }
  }

  float lq[2];
#pragma unroll
  for (int mt = 0; mt < 2; ++mt) {
    float s = lacc[mt][0] + lacc[mt][1] + lacc[mt][2] + lacc[mt][3];
    s += __shfl_xor(s, 16, 64);
    s += __shfl_xor(s, 32, 64);
    lq[mt] = s;
  }

#pragma unroll
  for (int mt = 0; mt < 2; ++mt) {
#pragma unroll
    for (int r = 0; r < 4; ++r) {
      float lr = __shfl(lq[mt], quad * 4 + r, 64);
      float inv = 1.0f / lr;
      unsigned short* crow =
          ctx + (size_t)(b * 2048 + q0 + wave * 32 + mt * 16 + quad * 4 + r) * 2048 +
          h * 128;
#pragma unroll
      for (int dt = 0; dt < 8; ++dt)
        crow[dt * 16 + l15] = f2bf(o[mt][dt][r] * inv);
    }
  }
}

// ---------------------------------------------------------------------------
extern "C" void kernel_launch(void* const* d_in, const int* in_sizes, int n_in,
                              void* d_out, int out_size, void* d_ws,
                              size_t ws_size, hipStream_t stream) {
  const float* q = (const float*)d_in[0];
  const float* k = (const float*)d_in[1];
  const float* v = (const float*)d_in[2];
  const float* Wq = (const float*)d_in[3];
  const float* bq = (const float*)d_in[4];
  const float* Wk = (const float*)d_in[5];
  const float* bk = (const float*)d_in[6];
  const float* Wv = (const float*)d_in[7];
  const float* bv = (const float*)d_in[8];
  const float* Wo = (const float*)d_in[9];
  const float* bo = (const float*)d_in[10];
  float* out = (float*)d_out;

  char* ws = (char*)d_ws;
  const size_t MB = 1024 * 1024;
  unsigned short* Xq  = (unsigned short*)(ws + 0 * MB);
  unsigned short* Xk  = (unsigned short*)(ws + 16 * MB);
  unsigned short* Xv  = (unsigned short*)(ws + 32 * MB);
  unsigned short* WqB = (unsigned short*)(ws + 48 * MB);
  unsigned short* WkB = (unsigned short*)(ws + 56 * MB);
  unsigned short* WvB = (unsigned short*)(ws + 64 * MB);
  unsigned short* WoB = (unsigned short*)(ws + 72 * MB);
  unsigned short* Qb  = (unsigned short*)(ws + 80 * MB);
  unsigned short* Kb  = (unsigned short*)(ws + 96 * MB);
  unsigned short* Vt  = (unsigned short*)(ws + 112 * MB);
  unsigned short* ctx = Xq;  // Xq dead after QKV projection

  cvt_kernel<<<20480, 256, 0, stream>>>(q, k, v, Wq, Wk, Wv, Wo, Xq, Xk, Xv,
                                        WqB, WkB, WvB, WoB);
  qkv_gemm256<<<dim3(8, 16, 3), 512, 0, stream>>>(Xq, Xk, Xv, WqB, WkB, WvB,
                                                  bq, bk, bv, Qb, Kb, Vt);
  attn_kernel<<<dim3(16, 16, 2), 256, 0, stream>>>(Qb, Kb, Vt, ctx);
  o_gemm<<<dim3(16, 32), 256, 0, stream>>>(ctx, WoB, bo, out);
}